// Round 7
// baseline (546.708 us; speedup 1.0000x reference)
//
#include <hip/hip_runtime.h>

typedef unsigned short u16;
typedef unsigned int u32;
typedef __bf16 bf16x8 __attribute__((ext_vector_type(8)));
typedef float f32x4 __attribute__((ext_vector_type(4)));

#define NTOK 8192
#define CDIM 768
#define HDIM 3072
#define NEXP 8
#define NPAIR 16384
#define HB 32   // hist/scatter blocks: HB*512 = NPAIR entries

__device__ __forceinline__ float b2f(u16 u){ u32 v = ((u32)u)<<16; float f; __builtin_memcpy(&f,&v,4); return f; }
__device__ __forceinline__ u16 f2b(float f){ u32 u; __builtin_memcpy(&u,&f,4); u32 r = (u + 0x7FFF + ((u>>16)&1)) >> 16; return (u16)r; }
__device__ __forceinline__ int iclamp(int v,int lo,int hi){ return v<lo?lo:(v>hi?hi:v); }

// gelu via A&S 7.1.26 erf (|err|<=1.5e-7 — far below bf16 rounding)
__device__ __forceinline__ float gelu_f(float v){
  float x = fabsf(v)*0.70710678118654752f;
  float t = __builtin_amdgcn_rcpf(1.0f + 0.3275911f*x);
  float p = ((((1.061405429f*t - 1.453152027f)*t + 1.421413741f)*t - 0.284496736f)*t + 0.254829592f)*t;
  float er = 1.0f - p*__expf(-x*x);
  er = copysignf(er, v);
  return 0.5f*v*(1.0f+er);
}

// async 16B global->LDS: per-lane global addr OK; LDS dest = wave-uniform base + lane*16
__device__ __forceinline__ void gl2l16(const void* g, void* l){
  __builtin_amdgcn_global_load_lds((const __attribute__((address_space(1))) void*)g,
                                   (__attribute__((address_space(3))) void*)l, 16, 0, 0);
}

// raw barrier (no implicit vmcnt drain) with memory fences
__device__ __forceinline__ void barf(){
  asm volatile("" ::: "memory");
  __builtin_amdgcn_s_barrier();
  asm volatile("" ::: "memory");
}
#define WAITVM4() asm volatile("s_waitcnt vmcnt(4)" ::: "memory")
#define WAITVM0() asm volatile("s_waitcnt vmcnt(0)" ::: "memory")
#define WAITLGKM0() asm volatile("s_waitcnt lgkmcnt(0)" ::: "memory")

// ---------------- dtype detect: fp32 viewed as u16 has garbage exponents ----------------
__global__ void detect_k(const u16* __restrict__ x, int* __restrict__ flagp){
  __shared__ int cnt;
  if (threadIdx.x==0) cnt=0;
  __syncthreads();
  int bad=0;
  for (int i=threadIdx.x; i<2048; i+=256){
    u16 u = x[i];
    int ex = (u>>7)&0xFF;
    if (ex >= 134) bad++;
  }
  if (bad) atomicAdd(&cnt, bad);
  __syncthreads();
  if (threadIdx.x==0) *flagp = (cnt > 32) ? 1 : 0;
}

// ---------------- convert (fp32->bf16) or copy (bf16), 4 elems/thread ----------------
__global__ __launch_bounds__(256) void conv_k(const void* __restrict__ src, u16* __restrict__ dst,
                                              int n4, const int* __restrict__ flagp){
  int i = blockIdx.x*256 + threadIdx.x;
  if (i >= n4) return;
  if (*flagp){
    float4 v = ((const float4*)src)[i];
    ushort4 o; o.x=f2b(v.x); o.y=f2b(v.y); o.z=f2b(v.z); o.w=f2b(v.w);
    ((ushort4*)dst)[i] = o;
  } else {
    ((ushort4*)dst)[i] = ((const ushort4*)src)[i];
  }
}

// ---------------- router: fp64-exact logits; NO ATOMICS (hist_k counts separately) ----------------
__global__ __launch_bounds__(256) void router_k(const void* __restrict__ xraw, const void* __restrict__ Wrraw,
    const int* __restrict__ flagp,
    int* __restrict__ tok_e, float* __restrict__ tok_w){
  int fp32f = *flagp;
  int tok = blockIdx.x*4 + (threadIdx.x>>6);
  int lane = threadIdx.x & 63;
  double acc[8];
  #pragma unroll
  for(int e=0;e<8;e++) acc[e]=0.0;
  for(int j=0;j<12;j++){
    int c = j*64 + lane;
    if (fp32f){
      double xv = (double)((const float*)xraw)[(size_t)tok*CDIM + c];
      const float* wr = (const float*)Wrraw + (size_t)c*8;
      float4 w0 = *(const float4*)wr;
      float4 w1 = *(const float4*)(wr+4);
      acc[0] += xv*(double)w0.x; acc[1] += xv*(double)w0.y;
      acc[2] += xv*(double)w0.z; acc[3] += xv*(double)w0.w;
      acc[4] += xv*(double)w1.x; acc[5] += xv*(double)w1.y;
      acc[6] += xv*(double)w1.z; acc[7] += xv*(double)w1.w;
    } else {
      double xv = (double)b2f(((const u16*)xraw)[(size_t)tok*CDIM + c]);
      uint4 wv = *(const uint4*)((const u16*)Wrraw + (size_t)c*8);
      acc[0] += xv*(double)b2f((u16)(wv.x&0xFFFF));
      acc[1] += xv*(double)b2f((u16)(wv.x>>16));
      acc[2] += xv*(double)b2f((u16)(wv.y&0xFFFF));
      acc[3] += xv*(double)b2f((u16)(wv.y>>16));
      acc[4] += xv*(double)b2f((u16)(wv.z&0xFFFF));
      acc[5] += xv*(double)b2f((u16)(wv.z>>16));
      acc[6] += xv*(double)b2f((u16)(wv.w&0xFFFF));
      acc[7] += xv*(double)b2f((u16)(wv.w>>16));
    }
  }
  #pragma unroll
  for(int e=0;e<8;e++){
    #pragma unroll
    for(int off=32;off>0;off>>=1) acc[e] += __shfl_down(acc[e], off);
  }
  if (lane==0){
    int i0=0; double b0=acc[0];
    #pragma unroll
    for(int e=1;e<8;e++) if(acc[e]>b0){ b0=acc[e]; i0=e; }
    int i1=(i0+1)&7; double b1v=-1e300;
    #pragma unroll
    for(int e=0;e<8;e++) if(e!=i0 && acc[e]>b1v){ b1v=acc[e]; i1=e; }
    double Z = 0.0;
    #pragma unroll
    for(int e=0;e<8;e++) Z += exp(acc[e]-b0);
    double pr0 = 1.0/Z;
    double pr1 = exp(b1v-b0)/Z;
    double s = pr0+pr1+1e-9;
    tok_e[2*tok]=i0; tok_e[2*tok+1]=i1;
    tok_w[2*tok]=(float)(pr0/s); tok_w[2*tok+1]=(float)(pr1/s);
  }
}

// ---------------- per-block expert histograms via ballot (zero atomics) ----------------
__global__ __launch_bounds__(256) void hist_k(const int* __restrict__ tok_e, int* __restrict__ bhist){
  int b = blockIdx.x, t = threadIdx.x;
  int wave = t>>6, lane = t&63;
  __shared__ int lh[4][8];
  int base = b*512 + wave*128 + lane;
  int e0 = tok_e[base]    & 7;
  int e1 = tok_e[base+64] & 7;
  #pragma unroll
  for(int e=0;e<8;e++){
    unsigned long long m0 = __ballot(e0==e);
    unsigned long long m1 = __ballot(e1==e);
    if (lane==0) lh[wave][e] = __popcll(m0) + __popcll(m1);
  }
  __syncthreads();
  if (t<8){
    int s=0;
    #pragma unroll
    for(int w=0;w<4;w++) s += lh[w][t];
    bhist[b*8+t] = s;
  }
}

// ---------------- scan: bhist -> offsets[9], per-block bases, utilization output ----------------
__global__ __launch_bounds__(64) void offsets2_k(const int* __restrict__ bhist, int* __restrict__ offsets,
                          int* __restrict__ bbase, void* __restrict__ dout, const int* __restrict__ flagp){
  __shared__ int cnt[8], off[8];
  int t = threadIdx.x;
  if (t<8){
    int s=0;
    for(int b=0;b<HB;b++) s += bhist[b*8+t];
    cnt[t]=s;
  }
  __syncthreads();
  if (t==0){
    int s=0;
    for(int e=0;e<8;e++){ off[e]=s; offsets[e]=s; s+=cnt[e]; }
    offsets[8]=s;
    int fp32f = *flagp;
    float inv = 1.f/((float)s + 1e-9f);
    for(int e=0;e<8;e++){
      float val = (float)cnt[e]*inv;
      if (fp32f) ((float*)dout)[(size_t)NTOK*CDIM + e] = val;
      else       ((u16*)dout)[(size_t)NTOK*CDIM + e]   = f2b(val);
    }
  }
  __syncthreads();
  if (t<8){
    int a = off[t];
    for(int b=0;b<HB;b++){ bbase[b*8+t] = a; a += bhist[b*8+t]; }
  }
}

// ---------------- deterministic scatter: rank = block base + wave prefix + intra-wave rank ----------------
__global__ __launch_bounds__(256) void scatter2_k(const int* __restrict__ tok_e,
    const int* __restrict__ bbase, int* __restrict__ pair_tok, int* __restrict__ tok_pos){
  int b = blockIdx.x, t = threadIdx.x;
  int wave = t>>6, lane = t&63;
  __shared__ int lh[4][8];
  int base = b*512 + wave*128 + lane;
  int i0 = base, i1 = base+64;
  int e0 = tok_e[i0] & 7;
  int e1 = tok_e[i1] & 7;
  unsigned long long lt = (1ULL<<lane)-1;
  int r0=0, r1=0;
  #pragma unroll
  for(int e=0;e<8;e++){
    unsigned long long m0 = __ballot(e0==e);
    unsigned long long m1 = __ballot(e1==e);
    if (lane==0) lh[wave][e] = __popcll(m0) + __popcll(m1);
    if (e0==e) r0 = __popcll(m0 & lt);
    if (e1==e) r1 = __popcll(m0) + __popcll(m1 & lt);
  }
  __syncthreads();
  int wb0=0, wb1=0;
  for(int w=0;w<wave;w++){ wb0 += lh[w][e0]; wb1 += lh[w][e1]; }
  int p0 = iclamp(bbase[b*8+e0] + wb0 + r0, 0, NPAIR-1);
  int p1 = iclamp(bbase[b*8+e1] + wb1 + r1, 0, NPAIR-1);
  pair_tok[p0] = i0>>1;
  pair_tok[p1] = i1>>1;
  tok_pos[i0] = p0;
  tok_pos[i1] = p1;
}

// ---------------- transpose per expert, fused dtype conversion ----------------
__global__ __launch_bounds__(256) void transpose_k(const void* __restrict__ inv, u16* __restrict__ out,
                                                   int R, int Cc, const int* __restrict__ flagp){
  __shared__ u16 T[64][65];
  int fp32f = *flagp;
  int ex = blockIdx.z;
  size_t base = (size_t)ex*R*Cc;
  out += base;
  int c0 = blockIdx.x*64, r0 = blockIdx.y*64;
  int tx = threadIdx.x & 31, ty = threadIdx.x >> 5;
  #pragma unroll
  for(int i=0;i<8;i++){
    int row = ty + i*8;
    size_t idx = base + (size_t)(r0+row)*Cc + c0 + tx*2;
    u32 v;
    if (fp32f){
      float2 f2v = *(const float2*)((const float*)inv + idx);
      v = (u32)f2b(f2v.x) | ((u32)f2b(f2v.y)<<16);
    } else {
      v = *(const u32*)((const u16*)inv + idx);
    }
    T[row][tx*2]   = (u16)(v&0xFFFF);
    T[row][tx*2+1] = (u16)(v>>16);
  }
  __syncthreads();
  #pragma unroll
  for(int i=0;i<8;i++){
    int row = ty + i*8;
    u32 lo = T[tx*2][row], hi = T[tx*2+1][row];
    *(u32*)(out + (size_t)(c0+row)*R + r0 + tx*2) = lo | (hi<<16);
  }
}

// ================= grouped GEMM: 128x128 tile, BK=32, TRIPLE-buffered counted-vmcnt =============
// XCD/L2-aware remap (R5 winner, unchanged): XCD k <- expert k, staging from its own L2.
// NEW schedule (components HW-proven in R4's passing run): per K-tile
//   STAGE(t+2) -> compute(t) -> s_waitcnt vmcnt(4) [confirms t+1; t+2's 4 loads stay in flight,
//   never drain-to-0] -> s_waitcnt lgkmcnt(0) [all ds_reads retired: closes the rule-18 race
//   across a raw barrier] -> s_barrier.
// Hazards: WAR (STAGE(t+2) overwrites buf[(t+2)%3] read by compute(t-1)) fenced by the
// end-of-(t-1) lgkm-drain + barrier; RAW (compute(t) needs ALL waves' stage-t) established by
// each wave's vmcnt wait at iter t-1 + that barrier. 3 bufs x 16 KB = 48 KB -> 3 blocks/CU.
// Swizzle (BK=32): row=64B=4 chunks; phys16B = logical ^ (row&3); staging pre-swizzles the
// GLOBAL source (rule 21: cl = (lane&3)^(srow&3)); ds_read phys chunk = quad^(row&3).
// EPI 0: gelu(acc+bias)->bf16   EPI 1: acc+bias->fp32
#define BM 128
#define BN 128
#define BK 32
#define BUFSZ (BM*BK)   // 4096 u16 = 8 KB

template<int EPI, int NSLABS_E>
__global__ __launch_bounds__(256, 3) void gemm_k(
    const u16* __restrict__ Abase, const int* __restrict__ pair_tok, int astride,
    const u16* __restrict__ Bt, const u16* __restrict__ bias,
    const int* __restrict__ offsets, int K, int N,
    u16* __restrict__ out_bf, float* __restrict__ out_f)
{
  constexpr int Q = 192*NSLABS_E;
  int j = blockIdx.x;
  int wid = (j&7)*Q + (j>>3);
  int slab = wid/192, s = wid - slab*192;
  int e  = slab / NSLABS_E;
  int ns = slab - e*NSLABS_E;
  int mb = s/3;
  int ny = s - mb*3;
  int m0 = mb*BM;
  int n0 = (ns*3 + ny)*BN;

  int seg0 = iclamp(offsets[e],   0, NPAIR);
  int seg1 = iclamp(offsets[e+1], seg0, NPAIR);
  int Me = seg1 - seg0;
  if (m0 >= Me) return;    // block-uniform exit

  alignas(16) __shared__ u16 As[3*BUFSZ];   // 24 KB
  alignas(16) __shared__ u16 Bs[3*BUFSZ];   // 24 KB

  int t = threadIdx.x;
  int wave = t>>6, lane = t&63;
  int wm = (wave>>1)*64, wn = (wave&1)*64;
  int lr = lane&15, quad = lane>>4;

  // staging: one gl2l16 = 64 lanes x 16B = 16 rows x 64B. lane row srow=lane>>2, phys chunk lane&3.
  int srow = lane>>2;
  int cl   = (lane&3) ^ (srow&3);
  const u16* aptr[2]; const u16* bptr[2];
  int lbase[2];
  const u16* bbase_ = Bt + (size_t)e*(size_t)N*K;
  #pragma unroll
  for(int i=0;i<2;i++){
    int tr = wave*32 + i*16 + srow;               // tile-local row 0..127
    int rr = iclamp(seg0 + m0 + tr, 0, seg1-1);
    int row = pair_tok ? iclamp(pair_tok[rr], 0, NTOK-1) : rr;
    aptr[i] = Abase + (size_t)row*astride + cl*8;
    bptr[i] = bbase_ + (size_t)(n0+tr)*K + cl*8;
    lbase[i] = (wave*32 + i*16)*BK;               // wave-uniform LDS base (u16 units)
  }

  f32x4 acc[4][4];
  #pragma unroll
  for(int i=0;i<4;i++)
    #pragma unroll
    for(int jj=0;jj<4;jj++) acc[i][jj]=(f32x4){0.f,0.f,0.f,0.f};

  int nt = K/BK;

  // prologue: stage tiles 0,1 into bufs 0,1; confirm tile 0 (4 of tile 1 stay in flight)
  #pragma unroll
  for(int i=0;i<2;i++){ gl2l16(aptr[i],      &As[lbase[i]]);        gl2l16(bptr[i],      &Bs[lbase[i]]); }
  #pragma unroll
  for(int i=0;i<2;i++){ gl2l16(aptr[i]+BK,   &As[BUFSZ+lbase[i]]);  gl2l16(bptr[i]+BK,   &Bs[BUFSZ+lbase[i]]); }
  WAITVM4();
  barf();

  int cur = 0;
  for(int kt=0; kt<nt; ++kt){
    // stage tile kt+2 into buffer (cur+2)%3
    if (kt+2 < nt){
      int b2 = cur+2; if (b2>=3) b2-=3;
      int ko = (kt+2)*BK;
      #pragma unroll
      for(int i=0;i<2;i++){
        gl2l16(aptr[i]+ko, &As[b2*BUFSZ+lbase[i]]);
        gl2l16(bptr[i]+ko, &Bs[b2*BUFSZ+lbase[i]]);
      }
    }
    // compute tile kt from buffer cur
    int cb = cur*BUFSZ;
    bf16x8 af[4], bfr[4];
    #pragma unroll
    for(int i=0;i<4;i++){
      int ra = wm+i*16+lr;
      int rb = wn+i*16+lr;
      af[i]  = *(const bf16x8*)(&As[cb + ra*BK + ((quad ^ (ra&3))*8)]);
      bfr[i] = *(const bf16x8*)(&Bs[cb + rb*BK + ((quad ^ (rb&3))*8)]);
    }
    __builtin_amdgcn_s_setprio(1);
    #pragma unroll
    for(int i=0;i<4;i++)
      #pragma unroll
      for(int jj=0;jj<4;jj++)
        acc[i][jj] = __builtin_amdgcn_mfma_f32_16x16x32_bf16(af[i], bfr[jj], acc[i][jj], 0,0,0);
    __builtin_amdgcn_s_setprio(0);
    // wait AFTER compute: tile kt+1 (issued at iter kt-1) must be resident for next iter
    if (kt+1 < nt){
      if (kt+2 < nt) WAITVM4();   // leaves tile kt+2's 4 loads in flight
      else           WAITVM0();   // tail: drain the last stage
    }
    WAITLGKM0();                  // all ds_reads retired before crossing the raw barrier
    barf();
    cur = cur+1; if (cur>=3) cur=0;
  }

  // epilogue: D layout col=lane&15, row=quad*4+reg  [verified m89/m91]
  #pragma unroll
  for(int i=0;i<4;i++){
    int mm_base = wm + i*16 + quad*4;
    #pragma unroll
    for(int jj=0;jj<4;jj++){
      int nn = n0 + wn + jj*16 + lr;
      float bv = b2f(bias[(size_t)e*N + nn]);
      #pragma unroll
      for(int rg=0;rg<4;rg++){
        int mm = m0 + mm_base + rg;
        if (mm < Me){
          int r = seg0 + mm;
          float v = acc[i][jj][rg] + bv;
          if (EPI==0) out_bf[(size_t)r*N + nn] = f2b(gelu_f(v));
          else        out_f[(size_t)r*N + nn] = v;
        }
      }
    }
  }
}

// ---------------- combine: out[tok] = w0*y[pos0] + w1*y[pos1] ----------------
__global__ __launch_bounds__(192) void combine_k(const float* __restrict__ y,
    const int* __restrict__ tok_pos, const float* __restrict__ tok_w,
    void* __restrict__ outv, const int* __restrict__ flagp){
  int fp32f = *flagp;
  int tkn = blockIdx.x;
  int c = threadIdx.x*4;
  int p0 = iclamp(tok_pos[2*tkn],   0, NPAIR-1);
  int p1 = iclamp(tok_pos[2*tkn+1], 0, NPAIR-1);
  float w0 = tok_w[2*tkn], w1 = tok_w[2*tkn+1];
  float4 a = *(const float4*)(y + (size_t)p0*CDIM + c);
  float4 b = *(const float4*)(y + (size_t)p1*CDIM + c);
  float4 o4;
  o4.x = w0*a.x + w1*b.x;
  o4.y = w0*a.y + w1*b.y;
  o4.z = w0*a.z + w1*b.z;
  o4.w = w0*a.w + w1*b.w;
  if (fp32f){
    *(float4*)((float*)outv + (size_t)tkn*CDIM + c) = o4;
  } else {
    ushort4 o;
    o.x = f2b(o4.x); o.y = f2b(o4.y); o.z = f2b(o4.z); o.w = f2b(o4.w);
    *(ushort4*)((u16*)outv + (size_t)tkn*CDIM + c) = o;
  }
}

extern "C" void kernel_launch(void* const* d_in, const int* in_sizes, int n_in,
                              void* d_out, int out_size, void* d_ws, size_t ws_size,
                              hipStream_t stream) {
  const void* x  = d_in[0];
  const void* Wr = d_in[1];
  const void* W1 = d_in[2];
  const void* b1 = d_in[3];
  const void* W2 = d_in[4];
  const void* b2 = d_in[5];

  // ws carve (all offsets multiple of 16)
  char* w = (char*)d_ws;
  int*   flagp    = (int*)w;                   // 4 B
  int*   offsets  = (int*)(w + 256);           // 9 ints
  int*   bhist    = (int*)(w + 512);           // 256 ints [512,1536)
  int*   bbase    = (int*)(w + 1536);          // 256 ints [1536,2560)
  int*   tok_e    = (int*)(w + 2560);          // 16384 ints [2560,68096)
  float* tok_w    = (float*)(w + 68096);       // [68096,133632)
  int*   tok_pos  = (int*)(w + 133632);        // [133632,199168)
  int*   pair_tok = (int*)(w + 199168);        // [199168,264704)
  u16*   b1c      = (u16*)(w + 264704);        // 49152 B [264704,313856)
  u16*   b2c      = (u16*)(w + 313856);        // 12288 B [313856,326144)
  u16*   xc       = (u16*)(w + 326144);        // 12582912 B -> 12909056
  u16*   W1t      = (u16*)(w + 12909056);      // [E][H][C] 37748736 B -> 50657792
  u16*   W2t      = W1t + (size_t)NEXP*CDIM*HDIM;      // [E][C][H] 37748736 B -> 88406528
  u16*   h        = W2t + (size_t)NEXP*CDIM*HDIM;      // [NPAIR][H] bf16 -> 189069824
  float* y        = (float*)(h + (size_t)NPAIR*HDIM);  // [NPAIR][C] fp32 -> 239401472
  size_t need = 239401472ull;
  if (ws_size < need) {
    hipMemsetAsync(d_out, 0, (size_t)out_size*2, stream);
    return;
  }

  detect_k<<<1, 256, 0, stream>>>((const u16*)x, flagp);
  conv_k<<<6144, 256, 0, stream>>>(x,  xc,  NTOK*CDIM/4, flagp);
  conv_k<<<24,   256, 0, stream>>>(b1, b1c, NEXP*HDIM/4, flagp);
  conv_k<<<6,    256, 0, stream>>>(b2, b2c, NEXP*CDIM/4, flagp);
  // W1 [E][C][H] -> W1t [E][H][C]; W2 [E][H][C] -> W2t [E][C][H]
  transpose_k<<<dim3(HDIM/64, CDIM/64, NEXP), 256, 0, stream>>>(W1, W1t, CDIM, HDIM, flagp);
  transpose_k<<<dim3(CDIM/64, HDIM/64, NEXP), 256, 0, stream>>>(W2, W2t, HDIM, CDIM, flagp);
  router_k<<<NTOK/4, 256, 0, stream>>>(x, Wr, flagp, tok_e, tok_w);
  hist_k<<<HB, 256, 0, stream>>>(tok_e, bhist);
  offsets2_k<<<1, 64, 0, stream>>>(bhist, offsets, bbase, d_out, flagp);
  scatter2_k<<<HB, 256, 0, stream>>>(tok_e, bbase, pair_tok, tok_pos);
  // GEMM1: h = gelu(x_gathered @ W1[e] + b1[e])   [Me x 3072] bf16
  gemm_k<0,8><<<12288, 256, 0, stream>>>(
      xc, pair_tok, CDIM, W1t, b1c, offsets, CDIM, HDIM, h, nullptr);
  // GEMM2: y = h @ W2[e] + b2[e]                  [Me x 768] fp32
  gemm_k<1,2><<<3072, 256, 0, stream>>>(
      h, nullptr, HDIM, W2t, b2c, offsets, HDIM, CDIM, nullptr, y);
  combine_k<<<NTOK, 192, 0, stream>>>(y, tok_pos, tok_w, d_out, flagp);
}

// Round 8
// 542.816 us; speedup vs baseline: 1.0072x; 1.0072x over previous
//
#include <hip/hip_runtime.h>

typedef unsigned short u16;
typedef unsigned int u32;
typedef __bf16 bf16x8 __attribute__((ext_vector_type(8)));
typedef float f32x4 __attribute__((ext_vector_type(4)));

#define NTOK 8192
#define CDIM 768
#define HDIM 3072
#define NEXP 8
#define NPAIR 16384
#define HB 32   // hist/scatter blocks: HB*512 = NPAIR entries

__device__ __forceinline__ float b2f(u16 u){ u32 v = ((u32)u)<<16; float f; __builtin_memcpy(&f,&v,4); return f; }
__device__ __forceinline__ u16 f2b(float f){ u32 u; __builtin_memcpy(&u,&f,4); u32 r = (u + 0x7FFF + ((u>>16)&1)) >> 16; return (u16)r; }
__device__ __forceinline__ int iclamp(int v,int lo,int hi){ return v<lo?lo:(v>hi?hi:v); }

// gelu via A&S 7.1.26 erf (|err|<=1.5e-7 — far below bf16 rounding)
__device__ __forceinline__ float gelu_f(float v){
  float x = fabsf(v)*0.70710678118654752f;
  float t = __builtin_amdgcn_rcpf(1.0f + 0.3275911f*x);
  float p = ((((1.061405429f*t - 1.453152027f)*t + 1.421413741f)*t - 0.284496736f)*t + 0.254829592f)*t;
  float er = 1.0f - p*__expf(-x*x);
  er = copysignf(er, v);
  return 0.5f*v*(1.0f+er);
}

// async 16B global->LDS: per-lane global addr OK; LDS dest = wave-uniform base + lane*16
__device__ __forceinline__ void gl2l16(const void* g, void* l){
  __builtin_amdgcn_global_load_lds((const __attribute__((address_space(1))) void*)g,
                                   (__attribute__((address_space(3))) void*)l, 16, 0, 0);
}

// raw barrier (no implicit vmcnt drain) with memory fences
__device__ __forceinline__ void barf(){
  asm volatile("" ::: "memory");
  __builtin_amdgcn_s_barrier();
  asm volatile("" ::: "memory");
}
#define WAITVM4() asm volatile("s_waitcnt vmcnt(4)" ::: "memory")
#define WAITVM0() asm volatile("s_waitcnt vmcnt(0)" ::: "memory")
#define WAITLGKM0() asm volatile("s_waitcnt lgkmcnt(0)" ::: "memory")

// ---------------- dtype detect: fp32 viewed as u16 has garbage exponents ----------------
__global__ void detect_k(const u16* __restrict__ x, int* __restrict__ flagp){
  __shared__ int cnt;
  if (threadIdx.x==0) cnt=0;
  __syncthreads();
  int bad=0;
  for (int i=threadIdx.x; i<2048; i+=256){
    u16 u = x[i];
    int ex = (u>>7)&0xFF;
    if (ex >= 134) bad++;
  }
  if (bad) atomicAdd(&cnt, bad);
  __syncthreads();
  if (threadIdx.x==0) *flagp = (cnt > 32) ? 1 : 0;
}

// ---------------- convert (fp32->bf16) or copy (bf16), 4 elems/thread ----------------
__global__ __launch_bounds__(256) void conv_k(const void* __restrict__ src, u16* __restrict__ dst,
                                              int n4, const int* __restrict__ flagp){
  int i = blockIdx.x*256 + threadIdx.x;
  if (i >= n4) return;
  if (*flagp){
    float4 v = ((const float4*)src)[i];
    ushort4 o; o.x=f2b(v.x); o.y=f2b(v.y); o.z=f2b(v.z); o.w=f2b(v.w);
    ((ushort4*)dst)[i] = o;
  } else {
    ((ushort4*)dst)[i] = ((const ushort4*)src)[i];
  }
}

// ---------------- router: fp64-exact logits; NO ATOMICS (hist_k counts separately) ----------------
__global__ __launch_bounds__(256) void router_k(const void* __restrict__ xraw, const void* __restrict__ Wrraw,
    const int* __restrict__ flagp,
    int* __restrict__ tok_e, float* __restrict__ tok_w){
  int fp32f = *flagp;
  int tok = blockIdx.x*4 + (threadIdx.x>>6);
  int lane = threadIdx.x & 63;
  double acc[8];
  #pragma unroll
  for(int e=0;e<8;e++) acc[e]=0.0;
  for(int j=0;j<12;j++){
    int c = j*64 + lane;
    if (fp32f){
      double xv = (double)((const float*)xraw)[(size_t)tok*CDIM + c];
      const float* wr = (const float*)Wrraw + (size_t)c*8;
      float4 w0 = *(const float4*)wr;
      float4 w1 = *(const float4*)(wr+4);
      acc[0] += xv*(double)w0.x; acc[1] += xv*(double)w0.y;
      acc[2] += xv*(double)w0.z; acc[3] += xv*(double)w0.w;
      acc[4] += xv*(double)w1.x; acc[5] += xv*(double)w1.y;
      acc[6] += xv*(double)w1.z; acc[7] += xv*(double)w1.w;
    } else {
      double xv = (double)b2f(((const u16*)xraw)[(size_t)tok*CDIM + c]);
      uint4 wv = *(const uint4*)((const u16*)Wrraw + (size_t)c*8);
      acc[0] += xv*(double)b2f((u16)(wv.x&0xFFFF));
      acc[1] += xv*(double)b2f((u16)(wv.x>>16));
      acc[2] += xv*(double)b2f((u16)(wv.y&0xFFFF));
      acc[3] += xv*(double)b2f((u16)(wv.y>>16));
      acc[4] += xv*(double)b2f((u16)(wv.z&0xFFFF));
      acc[5] += xv*(double)b2f((u16)(wv.z>>16));
      acc[6] += xv*(double)b2f((u16)(wv.w&0xFFFF));
      acc[7] += xv*(double)b2f((u16)(wv.w>>16));
    }
  }
  #pragma unroll
  for(int e=0;e<8;e++){
    #pragma unroll
    for(int off=32;off>0;off>>=1) acc[e] += __shfl_down(acc[e], off);
  }
  if (lane==0){
    int i0=0; double b0=acc[0];
    #pragma unroll
    for(int e=1;e<8;e++) if(acc[e]>b0){ b0=acc[e]; i0=e; }
    int i1=(i0+1)&7; double b1v=-1e300;
    #pragma unroll
    for(int e=0;e<8;e++) if(e!=i0 && acc[e]>b1v){ b1v=acc[e]; i1=e; }
    double Z = 0.0;
    #pragma unroll
    for(int e=0;e<8;e++) Z += exp(acc[e]-b0);
    double pr0 = 1.0/Z;
    double pr1 = exp(b1v-b0)/Z;
    double s = pr0+pr1+1e-9;
    tok_e[2*tok]=i0; tok_e[2*tok+1]=i1;
    tok_w[2*tok]=(float)(pr0/s); tok_w[2*tok+1]=(float)(pr1/s);
  }
}

// ---------------- per-block expert histograms via ballot (zero atomics) ----------------
__global__ __launch_bounds__(256) void hist_k(const int* __restrict__ tok_e, int* __restrict__ bhist){
  int b = blockIdx.x, t = threadIdx.x;
  int wave = t>>6, lane = t&63;
  __shared__ int lh[4][8];
  int base = b*512 + wave*128 + lane;
  int e0 = tok_e[base]    & 7;
  int e1 = tok_e[base+64] & 7;
  #pragma unroll
  for(int e=0;e<8;e++){
    unsigned long long m0 = __ballot(e0==e);
    unsigned long long m1 = __ballot(e1==e);
    if (lane==0) lh[wave][e] = __popcll(m0) + __popcll(m1);
  }
  __syncthreads();
  if (t<8){
    int s=0;
    #pragma unroll
    for(int w=0;w<4;w++) s += lh[w][t];
    bhist[b*8+t] = s;
  }
}

// ---------------- scan: bhist -> offsets[9], per-block bases, utilization output ----------------
__global__ __launch_bounds__(64) void offsets2_k(const int* __restrict__ bhist, int* __restrict__ offsets,
                          int* __restrict__ bbase, void* __restrict__ dout, const int* __restrict__ flagp){
  __shared__ int cnt[8], off[8];
  int t = threadIdx.x;
  if (t<8){
    int s=0;
    for(int b=0;b<HB;b++) s += bhist[b*8+t];
    cnt[t]=s;
  }
  __syncthreads();
  if (t==0){
    int s=0;
    for(int e=0;e<8;e++){ off[e]=s; offsets[e]=s; s+=cnt[e]; }
    offsets[8]=s;
    int fp32f = *flagp;
    float inv = 1.f/((float)s + 1e-9f);
    for(int e=0;e<8;e++){
      float val = (float)cnt[e]*inv;
      if (fp32f) ((float*)dout)[(size_t)NTOK*CDIM + e] = val;
      else       ((u16*)dout)[(size_t)NTOK*CDIM + e]   = f2b(val);
    }
  }
  __syncthreads();
  if (t<8){
    int a = off[t];
    for(int b=0;b<HB;b++){ bbase[b*8+t] = a; a += bhist[b*8+t]; }
  }
}

// ---------------- deterministic scatter: rank = block base + wave prefix + intra-wave rank ----------------
__global__ __launch_bounds__(256) void scatter2_k(const int* __restrict__ tok_e,
    const int* __restrict__ bbase, int* __restrict__ pair_tok, int* __restrict__ tok_pos){
  int b = blockIdx.x, t = threadIdx.x;
  int wave = t>>6, lane = t&63;
  __shared__ int lh[4][8];
  int base = b*512 + wave*128 + lane;
  int i0 = base, i1 = base+64;
  int e0 = tok_e[i0] & 7;
  int e1 = tok_e[i1] & 7;
  unsigned long long lt = (1ULL<<lane)-1;
  int r0=0, r1=0;
  #pragma unroll
  for(int e=0;e<8;e++){
    unsigned long long m0 = __ballot(e0==e);
    unsigned long long m1 = __ballot(e1==e);
    if (lane==0) lh[wave][e] = __popcll(m0) + __popcll(m1);
    if (e0==e) r0 = __popcll(m0 & lt);
    if (e1==e) r1 = __popcll(m0) + __popcll(m1 & lt);
  }
  __syncthreads();
  int wb0=0, wb1=0;
  for(int w=0;w<wave;w++){ wb0 += lh[w][e0]; wb1 += lh[w][e1]; }
  int p0 = iclamp(bbase[b*8+e0] + wb0 + r0, 0, NPAIR-1);
  int p1 = iclamp(bbase[b*8+e1] + wb1 + r1, 0, NPAIR-1);
  pair_tok[p0] = i0>>1;
  pair_tok[p1] = i1>>1;
  tok_pos[i0] = p0;
  tok_pos[i1] = p1;
}

// ---------------- transpose per expert, fused dtype conversion ----------------
__global__ __launch_bounds__(256) void transpose_k(const void* __restrict__ inv, u16* __restrict__ out,
                                                   int R, int Cc, const int* __restrict__ flagp){
  __shared__ u16 T[64][65];
  int fp32f = *flagp;
  int ex = blockIdx.z;
  size_t base = (size_t)ex*R*Cc;
  out += base;
  int c0 = blockIdx.x*64, r0 = blockIdx.y*64;
  int tx = threadIdx.x & 31, ty = threadIdx.x >> 5;
  #pragma unroll
  for(int i=0;i<8;i++){
    int row = ty + i*8;
    size_t idx = base + (size_t)(r0+row)*Cc + c0 + tx*2;
    u32 v;
    if (fp32f){
      float2 f2v = *(const float2*)((const float*)inv + idx);
      v = (u32)f2b(f2v.x) | ((u32)f2b(f2v.y)<<16);
    } else {
      v = *(const u32*)((const u16*)inv + idx);
    }
    T[row][tx*2]   = (u16)(v&0xFFFF);
    T[row][tx*2+1] = (u16)(v>>16);
  }
  __syncthreads();
  #pragma unroll
  for(int i=0;i<8;i++){
    int row = ty + i*8;
    u32 lo = T[tx*2][row], hi = T[tx*2+1][row];
    *(u32*)(out + (size_t)(c0+row)*R + r0 + tx*2) = lo | (hi<<16);
  }
}

// ================= grouped GEMM: 128x128 tile, BK=32, TRIPLE-buffered counted-vmcnt =============
// R7 schedule (correct on HW) + R0's VERIFIED BK=32 swizzle (the R7 regression was chunk^(row&3)
// -> 9.7M bank conflicts; R0's chunk ^ ((row>>1)&3) measured 0):
//   bank base = 16*(r&1) + 4*chunk; with chunk = quad ^ ((r>>1)&3) each (r&1,chunk) slot gets
//   exactly 2 lanes per 16-lane group -> 2 lanes/16B-span = free (m136).
// Schedule per K-tile: STAGE(t+2) -> compute(t) -> vmcnt(4) [confirms t+1; t+2's 4 loads stay
// in flight, never drain-to-0] -> lgkmcnt(0) [rule-18: ds_reads retired before raw barrier]
// -> s_barrier.  WAR fenced by end-of-(t-1) barrier; RAW by each wave's vmcnt at t-1 + barrier.
// 3 bufs x 16 KB = 48 KB -> 3 blocks/CU. XCD/L2 remap (R5) unchanged.
// EPI 0: gelu(acc+bias)->bf16   EPI 1: acc+bias->fp32
#define BM 128
#define BN 128
#define BK 32
#define BUFSZ (BM*BK)   // 4096 u16 = 8 KB

template<int EPI, int NSLABS_E>
__global__ __launch_bounds__(256, 3) void gemm_k(
    const u16* __restrict__ Abase, const int* __restrict__ pair_tok, int astride,
    const u16* __restrict__ Bt, const u16* __restrict__ bias,
    const int* __restrict__ offsets, int K, int N,
    u16* __restrict__ out_bf, float* __restrict__ out_f)
{
  constexpr int Q = 192*NSLABS_E;
  int j = blockIdx.x;
  int wid = (j&7)*Q + (j>>3);
  int slab = wid/192, s = wid - slab*192;
  int e  = slab / NSLABS_E;
  int ns = slab - e*NSLABS_E;
  int mb = s/3;
  int ny = s - mb*3;
  int m0 = mb*BM;
  int n0 = (ns*3 + ny)*BN;

  int seg0 = iclamp(offsets[e],   0, NPAIR);
  int seg1 = iclamp(offsets[e+1], seg0, NPAIR);
  int Me = seg1 - seg0;
  if (m0 >= Me) return;    // block-uniform exit

  alignas(16) __shared__ u16 As[3*BUFSZ];   // 24 KB
  alignas(16) __shared__ u16 Bs[3*BUFSZ];   // 24 KB

  int t = threadIdx.x;
  int wave = t>>6, lane = t&63;
  int wm = (wave>>1)*64, wn = (wave&1)*64;
  int lr = lane&15, quad = lane>>4;

  // staging: one gl2l16 = 64 lanes x 16B = 16 rows x 64B. lane row srow=lane>>2, phys chunk lane&3.
  // R0-verified pre-swizzle: logical source chunk cl = (lane&3) ^ ((srow>>1)&3)
  // (tile row tr = 16-aligned + srow, so (tr>>1)&3 == (srow>>1)&3).
  int srow = lane>>2;
  int cl   = (lane&3) ^ ((srow>>1)&3);
  const u16* aptr[2]; const u16* bptr[2];
  int lbase[2];
  const u16* bbase_ = Bt + (size_t)e*(size_t)N*K;
  #pragma unroll
  for(int i=0;i<2;i++){
    int tr = wave*32 + i*16 + srow;               // tile-local row 0..127
    int rr = iclamp(seg0 + m0 + tr, 0, seg1-1);
    int row = pair_tok ? iclamp(pair_tok[rr], 0, NTOK-1) : rr;
    aptr[i] = Abase + (size_t)row*astride + cl*8;
    bptr[i] = bbase_ + (size_t)(n0+tr)*K + cl*8;
    lbase[i] = (wave*32 + i*16)*BK;               // wave-uniform LDS base (u16 units)
  }

  f32x4 acc[4][4];
  #pragma unroll
  for(int i=0;i<4;i++)
    #pragma unroll
    for(int jj=0;jj<4;jj++) acc[i][jj]=(f32x4){0.f,0.f,0.f,0.f};

  int nt = K/BK;

  // prologue: stage tiles 0,1 into bufs 0,1; confirm tile 0 (4 of tile 1 stay in flight)
  #pragma unroll
  for(int i=0;i<2;i++){ gl2l16(aptr[i],      &As[lbase[i]]);        gl2l16(bptr[i],      &Bs[lbase[i]]); }
  #pragma unroll
  for(int i=0;i<2;i++){ gl2l16(aptr[i]+BK,   &As[BUFSZ+lbase[i]]);  gl2l16(bptr[i]+BK,   &Bs[BUFSZ+lbase[i]]); }
  WAITVM4();
  barf();

  int cur = 0;
  for(int kt=0; kt<nt; ++kt){
    // stage tile kt+2 into buffer (cur+2)%3
    if (kt+2 < nt){
      int b2 = cur+2; if (b2>=3) b2-=3;
      int ko = (kt+2)*BK;
      #pragma unroll
      for(int i=0;i<2;i++){
        gl2l16(aptr[i]+ko, &As[b2*BUFSZ+lbase[i]]);
        gl2l16(bptr[i]+ko, &Bs[b2*BUFSZ+lbase[i]]);
      }
    }
    // compute tile kt from buffer cur; ds_read chunk = quad ^ ((row>>1)&3)  [R0-verified]
    int cb = cur*BUFSZ;
    bf16x8 af[4], bfr[4];
    #pragma unroll
    for(int i=0;i<4;i++){
      int ra = wm+i*16+lr;
      int rb = wn+i*16+lr;
      af[i]  = *(const bf16x8*)(&As[cb + ra*BK + ((quad ^ ((ra>>1)&3))*8)]);
      bfr[i] = *(const bf16x8*)(&Bs[cb + rb*BK + ((quad ^ ((rb>>1)&3))*8)]);
    }
    __builtin_amdgcn_s_setprio(1);
    #pragma unroll
    for(int i=0;i<4;i++)
      #pragma unroll
      for(int jj=0;jj<4;jj++)
        acc[i][jj] = __builtin_amdgcn_mfma_f32_16x16x32_bf16(af[i], bfr[jj], acc[i][jj], 0,0,0);
    __builtin_amdgcn_s_setprio(0);
    // wait AFTER compute: tile kt+1 (issued at iter kt-1) must be resident for next iter
    if (kt+1 < nt){
      if (kt+2 < nt) WAITVM4();   // leaves tile kt+2's 4 loads in flight
      else           WAITVM0();   // tail: drain the last stage
    }
    WAITLGKM0();                  // all ds_reads retired before crossing the raw barrier
    barf();
    cur = cur+1; if (cur>=3) cur=0;
  }

  // epilogue: D layout col=lane&15, row=quad*4+reg  [verified m89/m91]
  #pragma unroll
  for(int i=0;i<4;i++){
    int mm_base = wm + i*16 + quad*4;
    #pragma unroll
    for(int jj=0;jj<4;jj++){
      int nn = n0 + wn + jj*16 + lr;
      float bv = b2f(bias[(size_t)e*N + nn]);
      #pragma unroll
      for(int rg=0;rg<4;rg++){
        int mm = m0 + mm_base + rg;
        if (mm < Me){
          int r = seg0 + mm;
          float v = acc[i][jj][rg] + bv;
          if (EPI==0) out_bf[(size_t)r*N + nn] = f2b(gelu_f(v));
          else        out_f[(size_t)r*N + nn] = v;
        }
      }
    }
  }
}

// ---------------- combine: out[tok] = w0*y[pos0] + w1*y[pos1] ----------------
__global__ __launch_bounds__(192) void combine_k(const float* __restrict__ y,
    const int* __restrict__ tok_pos, const float* __restrict__ tok_w,
    void* __restrict__ outv, const int* __restrict__ flagp){
  int fp32f = *flagp;
  int tkn = blockIdx.x;
  int c = threadIdx.x*4;
  int p0 = iclamp(tok_pos[2*tkn],   0, NPAIR-1);
  int p1 = iclamp(tok_pos[2*tkn+1], 0, NPAIR-1);
  float w0 = tok_w[2*tkn], w1 = tok_w[2*tkn+1];
  float4 a = *(const float4*)(y + (size_t)p0*CDIM + c);
  float4 b = *(const float4*)(y + (size_t)p1*CDIM + c);
  float4 o4;
  o4.x = w0*a.x + w1*b.x;
  o4.y = w0*a.y + w1*b.y;
  o4.z = w0*a.z + w1*b.z;
  o4.w = w0*a.w + w1*b.w;
  if (fp32f){
    *(float4*)((float*)outv + (size_t)tkn*CDIM + c) = o4;
  } else {
    ushort4 o;
    o.x = f2b(o4.x); o.y = f2b(o4.y); o.z = f2b(o4.z); o.w = f2b(o4.w);
    *(ushort4*)((u16*)outv + (size_t)tkn*CDIM + c) = o;
  }
}

extern "C" void kernel_launch(void* const* d_in, const int* in_sizes, int n_in,
                              void* d_out, int out_size, void* d_ws, size_t ws_size,
                              hipStream_t stream) {
  const void* x  = d_in[0];
  const void* Wr = d_in[1];
  const void* W1 = d_in[2];
  const void* b1 = d_in[3];
  const void* W2 = d_in[4];
  const void* b2 = d_in[5];

  // ws carve (all offsets multiple of 16)
  char* w = (char*)d_ws;
  int*   flagp    = (int*)w;                   // 4 B
  int*   offsets  = (int*)(w + 256);           // 9 ints
  int*   bhist    = (int*)(w + 512);           // 256 ints [512,1536)
  int*   bbase    = (int*)(w + 1536);          // 256 ints [1536,2560)
  int*   tok_e    = (int*)(w + 2560);          // 16384 ints [2560,68096)
  float* tok_w    = (float*)(w + 68096);       // [68096,133632)
  int*   tok_pos  = (int*)(w + 133632);        // [133632,199168)
  int*   pair_tok = (int*)(w + 199168);        // [199168,264704)
  u16*   b1c      = (u16*)(w + 264704);        // 49152 B [264704,313856)
  u16*   b2c      = (u16*)(w + 313856);        // 12288 B [313856,326144)
  u16*   xc       = (u16*)(w + 326144);        // 12582912 B -> 12909056
  u16*   W1t      = (u16*)(w + 12909056);      // [E][H][C] 37748736 B -> 50657792
  u16*   W2t      = W1t + (size_t)NEXP*CDIM*HDIM;      // [E][C][H] 37748736 B -> 88406528
  u16*   h        = W2t + (size_t)NEXP*CDIM*HDIM;      // [NPAIR][H] bf16 -> 189069824
  float* y        = (float*)(h + (size_t)NPAIR*HDIM);  // [NPAIR][C] fp32 -> 239401472
  size_t need = 239401472ull;
  if (ws_size < need) {
    hipMemsetAsync(d_out, 0, (size_t)out_size*2, stream);
    return;
  }

  detect_k<<<1, 256, 0, stream>>>((const u16*)x, flagp);
  conv_k<<<6144, 256, 0, stream>>>(x,  xc,  NTOK*CDIM/4, flagp);
  conv_k<<<24,   256, 0, stream>>>(b1, b1c, NEXP*HDIM/4, flagp);
  conv_k<<<6,    256, 0, stream>>>(b2, b2c, NEXP*CDIM/4, flagp);
  // W1 [E][C][H] -> W1t [E][H][C]; W2 [E][H][C] -> W2t [E][C][H]
  transpose_k<<<dim3(HDIM/64, CDIM/64, NEXP), 256, 0, stream>>>(W1, W1t, CDIM, HDIM, flagp);
  transpose_k<<<dim3(CDIM/64, HDIM/64, NEXP), 256, 0, stream>>>(W2, W2t, HDIM, CDIM, flagp);
  router_k<<<NTOK/4, 256, 0, stream>>>(x, Wr, flagp, tok_e, tok_w);
  hist_k<<<HB, 256, 0, stream>>>(tok_e, bhist);
  offsets2_k<<<1, 64, 0, stream>>>(bhist, offsets, bbase, d_out, flagp);
  scatter2_k<<<HB, 256, 0, stream>>>(tok_e, bbase, pair_tok, tok_pos);
  // GEMM1: h = gelu(x_gathered @ W1[e] + b1[e])   [Me x 3072] bf16
  gemm_k<0,8><<<12288, 256, 0, stream>>>(
      xc, pair_tok, CDIM, W1t, b1c, offsets, CDIM, HDIM, h, nullptr);
  // GEMM2: y = h @ W2[e] + b2[e]                  [Me x 768] fp32
  gemm_k<1,2><<<3072, 256, 0, stream>>>(
      h, nullptr, HDIM, W2t, b2c, offsets, HDIM, CDIM, nullptr, y);
  combine_k<<<NTOK, 192, 0, stream>>>(y, tok_pos, tok_w, d_out, flagp);
}

// Round 9
// 506.957 us; speedup vs baseline: 1.0784x; 1.0707x over previous
//
#include <hip/hip_runtime.h>

typedef unsigned short u16;
typedef unsigned int u32;
typedef __bf16 bf16x8 __attribute__((ext_vector_type(8)));
typedef float f32x4 __attribute__((ext_vector_type(4)));

#define NTOK 8192
#define CDIM 768
#define HDIM 3072
#define NEXP 8
#define NPAIR 16384
#define HB 32   // hist/scatter blocks: HB*512 = NPAIR entries

__device__ __forceinline__ float b2f(u16 u){ u32 v = ((u32)u)<<16; float f; __builtin_memcpy(&f,&v,4); return f; }
__device__ __forceinline__ u16 f2b(float f){ u32 u; __builtin_memcpy(&u,&f,4); u32 r = (u + 0x7FFF + ((u>>16)&1)) >> 16; return (u16)r; }
__device__ __forceinline__ int iclamp(int v,int lo,int hi){ return v<lo?lo:(v>hi?hi:v); }

// gelu via A&S 7.1.26 erf (|err|<=1.5e-7 — far below bf16 rounding)
__device__ __forceinline__ float gelu_f(float v){
  float x = fabsf(v)*0.70710678118654752f;
  float t = __builtin_amdgcn_rcpf(1.0f + 0.3275911f*x);
  float p = ((((1.061405429f*t - 1.453152027f)*t + 1.421413741f)*t - 0.284496736f)*t + 0.254829592f)*t;
  float er = 1.0f - p*__expf(-x*x);
  er = copysignf(er, v);
  return 0.5f*v*(1.0f+er);
}

// async 16B global->LDS: per-lane global addr OK; LDS dest = wave-uniform base + lane*16
__device__ __forceinline__ void gl2l16(const void* g, void* l){
  __builtin_amdgcn_global_load_lds((const __attribute__((address_space(1))) void*)g,
                                   (__attribute__((address_space(3))) void*)l, 16, 0, 0);
}

// ---------------- dtype detect: fp32 viewed as u16 has garbage exponents ----------------
__global__ void detect_k(const u16* __restrict__ x, int* __restrict__ flagp){
  __shared__ int cnt;
  if (threadIdx.x==0) cnt=0;
  __syncthreads();
  int bad=0;
  for (int i=threadIdx.x; i<2048; i+=256){
    u16 u = x[i];
    int ex = (u>>7)&0xFF;
    if (ex >= 134) bad++;
  }
  if (bad) atomicAdd(&cnt, bad);
  __syncthreads();
  if (threadIdx.x==0) *flagp = (cnt > 32) ? 1 : 0;
}

// ================= mega_prep: router + transpose(W1) + transpose(W2) + conv x/b1/b2 ============
// All sub-jobs depend only on {x, Wr, W1, W2, b1, b2, flagp} — mutually independent, so one
// launch co-schedules them: router's latency-bound fp64 waves overlap the transposes' and
// convs' bandwidth waves instead of running serially (was 6 launches, strictly ordered).
// Sub-grid layout (flat blockIdx.x, router FIRST so its long-latency waves start earliest):
//   [0, 2048)            router        (was router_k<<<2048,256>>>)
//   [2048, 6656)         transpose W1  (was <<<dim3(48,12,8),256>>>, R=CDIM, Cc=HDIM)
//   [6656, 11264)        transpose W2  (was <<<dim3(12,48,8),256>>>, R=HDIM, Cc=CDIM)
//   [11264, 17408)       conv x->xc    (6144)
//   [17408, 17432)       conv b1->b1c  (24)
//   [17432, 17438)       conv b2->b2c  (6)
// Inner bodies are byte-identical to the R6/R8-verified kernels; only index derivation changed.
#define MEGA_NB 17438

__global__ __launch_bounds__(256) void mega_prep(
    const void* __restrict__ x, const void* __restrict__ Wr,
    const void* __restrict__ W1, const void* __restrict__ W2,
    const void* __restrict__ b1, const void* __restrict__ b2,
    const int* __restrict__ flagp,
    u16* __restrict__ xc, u16* __restrict__ b1c, u16* __restrict__ b2c,
    u16* __restrict__ W1t, u16* __restrict__ W2t,
    int* __restrict__ tok_e, float* __restrict__ tok_w)
{
  __shared__ u16 T[64][65];     // used by transpose branches only
  int gid = blockIdx.x;
  int t = threadIdx.x;
  int fp32f = *flagp;

  if (gid < 2048){
    // ---------------- router body (verbatim) ----------------
    int tok = gid*4 + (t>>6);
    int lane = t & 63;
    double acc[8];
    #pragma unroll
    for(int e=0;e<8;e++) acc[e]=0.0;
    for(int j=0;j<12;j++){
      int c = j*64 + lane;
      if (fp32f){
        double xv = (double)((const float*)x)[(size_t)tok*CDIM + c];
        const float* wr = (const float*)Wr + (size_t)c*8;
        float4 w0 = *(const float4*)wr;
        float4 w1 = *(const float4*)(wr+4);
        acc[0] += xv*(double)w0.x; acc[1] += xv*(double)w0.y;
        acc[2] += xv*(double)w0.z; acc[3] += xv*(double)w0.w;
        acc[4] += xv*(double)w1.x; acc[5] += xv*(double)w1.y;
        acc[6] += xv*(double)w1.z; acc[7] += xv*(double)w1.w;
      } else {
        double xv = (double)b2f(((const u16*)x)[(size_t)tok*CDIM + c]);
        uint4 wv = *(const uint4*)((const u16*)Wr + (size_t)c*8);
        acc[0] += xv*(double)b2f((u16)(wv.x&0xFFFF));
        acc[1] += xv*(double)b2f((u16)(wv.x>>16));
        acc[2] += xv*(double)b2f((u16)(wv.y&0xFFFF));
        acc[3] += xv*(double)b2f((u16)(wv.y>>16));
        acc[4] += xv*(double)b2f((u16)(wv.z&0xFFFF));
        acc[5] += xv*(double)b2f((u16)(wv.z>>16));
        acc[6] += xv*(double)b2f((u16)(wv.w&0xFFFF));
        acc[7] += xv*(double)b2f((u16)(wv.w>>16));
      }
    }
    #pragma unroll
    for(int e=0;e<8;e++){
      #pragma unroll
      for(int off=32;off>0;off>>=1) acc[e] += __shfl_down(acc[e], off);
    }
    if (lane==0){
      int i0=0; double b0=acc[0];
      #pragma unroll
      for(int e=1;e<8;e++) if(acc[e]>b0){ b0=acc[e]; i0=e; }
      int i1=(i0+1)&7; double b1v=-1e300;
      #pragma unroll
      for(int e=0;e<8;e++) if(e!=i0 && acc[e]>b1v){ b1v=acc[e]; i1=e; }
      double Z = 0.0;
      #pragma unroll
      for(int e=0;e<8;e++) Z += exp(acc[e]-b0);
      double pr0 = 1.0/Z;
      double pr1 = exp(b1v-b0)/Z;
      double s = pr0+pr1+1e-9;
      tok_e[2*tok]=i0; tok_e[2*tok+1]=i1;
      tok_w[2*tok]=(float)(pr0/s); tok_w[2*tok+1]=(float)(pr1/s);
    }
    return;
  }

  if (gid < 11264){
    // ---------------- transpose body (verbatim, flat->3D decode) ----------------
    const void* inv; u16* outp; int R, Cc, bx, by, bz;
    if (gid < 6656){
      int id = gid - 2048;                 // W1: gx=48 (Cc/64), gy=12 (R/64), gz=8
      bz = id/576; int r = id - bz*576; by = r/48; bx = r - by*48;
      inv = W1; outp = W1t; R = CDIM; Cc = HDIM;
    } else {
      int id = gid - 6656;                 // W2: gx=12, gy=48, gz=8
      bz = id/576; int r = id - bz*576; by = r/12; bx = r - by*12;
      inv = W2; outp = W2t; R = HDIM; Cc = CDIM;
    }
    size_t base = (size_t)bz*R*Cc;
    u16* out = outp + base;
    int c0 = bx*64, r0 = by*64;
    int tx = t & 31, ty = t >> 5;
    #pragma unroll
    for(int i=0;i<8;i++){
      int row = ty + i*8;
      size_t idx = base + (size_t)(r0+row)*Cc + c0 + tx*2;
      u32 v;
      if (fp32f){
        float2 f2v = *(const float2*)((const float*)inv + idx);
        v = (u32)f2b(f2v.x) | ((u32)f2b(f2v.y)<<16);
      } else {
        v = *(const u32*)((const u16*)inv + idx);
      }
      T[row][tx*2]   = (u16)(v&0xFFFF);
      T[row][tx*2+1] = (u16)(v>>16);
    }
    __syncthreads();
    #pragma unroll
    for(int i=0;i<8;i++){
      int row = ty + i*8;
      u32 lo = T[tx*2][row], hi = T[tx*2+1][row];
      *(u32*)(out + (size_t)(c0+row)*R + r0 + tx*2) = lo | (hi<<16);
    }
    return;
  }

  // ---------------- conv bodies (verbatim) ----------------
  const void* src; u16* dst; int n4, i;
  if (gid < 17408){ src = x;  dst = xc;  n4 = NTOK*CDIM/4; i = (gid-11264)*256 + t; }
  else if (gid < 17432){ src = b1; dst = b1c; n4 = NEXP*HDIM/4; i = (gid-17408)*256 + t; }
  else { src = b2; dst = b2c; n4 = NEXP*CDIM/4; i = (gid-17432)*256 + t; }
  if (i >= n4) return;
  if (fp32f){
    float4 v = ((const float4*)src)[i];
    ushort4 o; o.x=f2b(v.x); o.y=f2b(v.y); o.z=f2b(v.z); o.w=f2b(v.w);
    ((ushort4*)dst)[i] = o;
  } else {
    ((ushort4*)dst)[i] = ((const ushort4*)src)[i];
  }
}

// ---------------- per-block expert histograms via ballot (zero atomics) ----------------
__global__ __launch_bounds__(256) void hist_k(const int* __restrict__ tok_e, int* __restrict__ bhist){
  int b = blockIdx.x, t = threadIdx.x;
  int wave = t>>6, lane = t&63;
  __shared__ int lh[4][8];
  int base = b*512 + wave*128 + lane;
  int e0 = tok_e[base]    & 7;
  int e1 = tok_e[base+64] & 7;
  #pragma unroll
  for(int e=0;e<8;e++){
    unsigned long long m0 = __ballot(e0==e);
    unsigned long long m1 = __ballot(e1==e);
    if (lane==0) lh[wave][e] = __popcll(m0) + __popcll(m1);
  }
  __syncthreads();
  if (t<8){
    int s=0;
    #pragma unroll
    for(int w=0;w<4;w++) s += lh[w][t];
    bhist[b*8+t] = s;
  }
}

// ---------------- scan: bhist -> offsets[9], per-block bases, utilization output ----------------
__global__ __launch_bounds__(64) void offsets2_k(const int* __restrict__ bhist, int* __restrict__ offsets,
                          int* __restrict__ bbase, void* __restrict__ dout, const int* __restrict__ flagp){
  __shared__ int cnt[8], off[8];
  int t = threadIdx.x;
  if (t<8){
    int s=0;
    for(int b=0;b<HB;b++) s += bhist[b*8+t];
    cnt[t]=s;
  }
  __syncthreads();
  if (t==0){
    int s=0;
    for(int e=0;e<8;e++){ off[e]=s; offsets[e]=s; s+=cnt[e]; }
    offsets[8]=s;
    int fp32f = *flagp;
    float inv = 1.f/((float)s + 1e-9f);
    for(int e=0;e<8;e++){
      float val = (float)cnt[e]*inv;
      if (fp32f) ((float*)dout)[(size_t)NTOK*CDIM + e] = val;
      else       ((u16*)dout)[(size_t)NTOK*CDIM + e]   = f2b(val);
    }
  }
  __syncthreads();
  if (t<8){
    int a = off[t];
    for(int b=0;b<HB;b++){ bbase[b*8+t] = a; a += bhist[b*8+t]; }
  }
}

// ---------------- deterministic scatter: rank = block base + wave prefix + intra-wave rank ----------------
__global__ __launch_bounds__(256) void scatter2_k(const int* __restrict__ tok_e,
    const int* __restrict__ bbase, int* __restrict__ pair_tok, int* __restrict__ tok_pos){
  int b = blockIdx.x, t = threadIdx.x;
  int wave = t>>6, lane = t&63;
  __shared__ int lh[4][8];
  int base = b*512 + wave*128 + lane;
  int i0 = base, i1 = base+64;
  int e0 = tok_e[i0] & 7;
  int e1 = tok_e[i1] & 7;
  unsigned long long lt = (1ULL<<lane)-1;
  int r0=0, r1=0;
  #pragma unroll
  for(int e=0;e<8;e++){
    unsigned long long m0 = __ballot(e0==e);
    unsigned long long m1 = __ballot(e1==e);
    if (lane==0) lh[wave][e] = __popcll(m0) + __popcll(m1);
    if (e0==e) r0 = __popcll(m0 & lt);
    if (e1==e) r1 = __popcll(m0) + __popcll(m1 & lt);
  }
  __syncthreads();
  int wb0=0, wb1=0;
  for(int w=0;w<wave;w++){ wb0 += lh[w][e0]; wb1 += lh[w][e1]; }
  int p0 = iclamp(bbase[b*8+e0] + wb0 + r0, 0, NPAIR-1);
  int p1 = iclamp(bbase[b*8+e1] + wb1 + r1, 0, NPAIR-1);
  pair_tok[p0] = i0>>1;
  pair_tok[p1] = i1>>1;
  tok_pos[i0] = p0;
  tok_pos[i1] = p1;
}

// ================= grouped GEMM: 128x128 tile, BK=64, 2-phase + XCD/L2-aware remap ==============
// R6 champion kernel, VERBATIM (155/136 us measured). Double-buffer BK=64, prefetch next tile's
// global_load_lds, __syncthreads drain per K-tile, 2 blocks/CU. XCD-binding remap: XCD k <-
// expert k so B panels + expert A rows stay in that XCD's 4 MB L2 (the R5 lever: staging from
// L2 instead of the ~4.4 TB/s chip-wide L3 path). Chunk-XOR swizzle phys16B = logical^(row&7)
// pre-swizzled on the GLOBAL source (rule 21); 0 bank conflicts measured.
// EPI 0: gelu(acc+bias)->bf16   EPI 1: acc+bias->fp32
#define BM 128
#define BN 128
#define BK 64

template<int EPI, int NSLABS_E>
__global__ __launch_bounds__(256) void gemm_k(
    const u16* __restrict__ Abase, const int* __restrict__ pair_tok, int astride,
    const u16* __restrict__ Bt, const u16* __restrict__ bias,
    const int* __restrict__ offsets, int K, int N,
    u16* __restrict__ out_bf, float* __restrict__ out_f)
{
  constexpr int Q = 192*NSLABS_E;
  int j = blockIdx.x;
  int wid = (j&7)*Q + (j>>3);
  int slab = wid/192, s = wid - slab*192;
  int e  = slab / NSLABS_E;
  int ns = slab - e*NSLABS_E;
  int mb = s/3;
  int ny = s - mb*3;
  int m0 = mb*BM;
  int n0 = (ns*3 + ny)*BN;

  int seg0 = iclamp(offsets[e],   0, NPAIR);
  int seg1 = iclamp(offsets[e+1], seg0, NPAIR);
  int Me = seg1 - seg0;
  if (m0 >= Me) return;

  alignas(16) __shared__ u16 As[2*BM*BK];   // 32 KB
  alignas(16) __shared__ u16 Bs[2*BM*BK];   // 32 KB

  int t = threadIdx.x;
  int wave = t>>6, lane = t&63;
  int wm = (wave>>1)*64, wn = (wave&1)*64;
  int lr = lane&15, quad = lane>>4;

  int srow = lane>>3;
  int cl   = (lane&7) ^ srow;
  const u16* aptr[4]; const u16* bptr[4];
  int lbase[4];
  const u16* bbase_ = Bt + (size_t)e*(size_t)N*K;
  #pragma unroll
  for(int i=0;i<4;i++){
    int tr = wave*32 + i*8 + srow;                 // tile-local row 0..127
    int rr = iclamp(seg0 + m0 + tr, 0, seg1-1);
    int row = pair_tok ? iclamp(pair_tok[rr], 0, NTOK-1) : rr;
    aptr[i] = Abase + (size_t)row*astride + cl*8;
    bptr[i] = bbase_ + (size_t)(n0+tr)*K + cl*8;
    lbase[i] = (wave*32 + i*8)*BK;                 // wave-uniform LDS base (u16 units)
  }

  f32x4 acc[4][4];
  #pragma unroll
  for(int i=0;i<4;i++)
    #pragma unroll
    for(int jj=0;jj<4;jj++) acc[i][jj]=(f32x4){0.f,0.f,0.f,0.f};

  #pragma unroll
  for(int i=0;i<4;i++){ gl2l16(aptr[i], &As[lbase[i]]); gl2l16(bptr[i], &Bs[lbase[i]]); }
  __syncthreads();   // vmcnt(0) drain + barrier: tile 0 resident

  int nt = K/BK;
  int cb = 0;
  for(int kt=0; kt<nt; ++kt){
    if (kt+1 < nt){
      int k0 = (kt+1)*BK;
      int nb = cb ^ (BM*BK);
      #pragma unroll
      for(int i=0;i<4;i++){ gl2l16(aptr[i]+k0, &As[nb+lbase[i]]); gl2l16(bptr[i]+k0, &Bs[nb+lbase[i]]); }
    }
    bf16x8 af[4][2], bfr[4][2];
    #pragma unroll
    for(int i=0;i<4;i++){
      int ra = wm+i*16+lr;
      int rb = wn+i*16+lr;
      #pragma unroll
      for(int ks=0;ks<2;ks++){
        af[i][ks]  = *(const bf16x8*)(&As[cb + ra*BK + ((ks*4+quad) ^ (ra&7))*8]);
        bfr[i][ks] = *(const bf16x8*)(&Bs[cb + rb*BK + ((ks*4+quad) ^ (rb&7))*8]);
      }
    }
    #pragma unroll
    for(int ks=0;ks<2;ks++)
      #pragma unroll
      for(int i=0;i<4;i++)
        #pragma unroll
        for(int jj=0;jj<4;jj++)
          acc[i][jj] = __builtin_amdgcn_mfma_f32_16x16x32_bf16(af[i][ks], bfr[jj][ks], acc[i][jj], 0,0,0);
    __syncthreads();
    cb ^= (BM*BK);
  }

  // epilogue: D layout col=lane&15, row=quad*4+reg  [verified m89/m91]
  #pragma unroll
  for(int i=0;i<4;i++){
    int mm_base = wm + i*16 + quad*4;
    #pragma unroll
    for(int jj=0;jj<4;jj++){
      int nn = n0 + wn + jj*16 + lr;
      float bv = b2f(bias[(size_t)e*N + nn]);
      #pragma unroll
      for(int rg=0;rg<4;rg++){
        int mm = m0 + mm_base + rg;
        if (mm < Me){
          int r = seg0 + mm;
          float v = acc[i][jj][rg] + bv;
          if (EPI==0) out_bf[(size_t)r*N + nn] = f2b(gelu_f(v));
          else        out_f[(size_t)r*N + nn] = v;
        }
      }
    }
  }
}

// ---------------- combine: out[tok] = w0*y[pos0] + w1*y[pos1] ----------------
__global__ __launch_bounds__(192) void combine_k(const float* __restrict__ y,
    const int* __restrict__ tok_pos, const float* __restrict__ tok_w,
    void* __restrict__ outv, const int* __restrict__ flagp){
  int fp32f = *flagp;
  int tkn = blockIdx.x;
  int c = threadIdx.x*4;
  int p0 = iclamp(tok_pos[2*tkn],   0, NPAIR-1);
  int p1 = iclamp(tok_pos[2*tkn+1], 0, NPAIR-1);
  float w0 = tok_w[2*tkn], w1 = tok_w[2*tkn+1];
  float4 a = *(const float4*)(y + (size_t)p0*CDIM + c);
  float4 b = *(const float4*)(y + (size_t)p1*CDIM + c);
  float4 o4;
  o4.x = w0*a.x + w1*b.x;
  o4.y = w0*a.y + w1*b.y;
  o4.z = w0*a.z + w1*b.z;
  o4.w = w0*a.w + w1*b.w;
  if (fp32f){
    *(float4*)((float*)outv + (size_t)tkn*CDIM + c) = o4;
  } else {
    ushort4 o;
    o.x = f2b(o4.x); o.y = f2b(o4.y); o.z = f2b(o4.z); o.w = f2b(o4.w);
    *(ushort4*)((u16*)outv + (size_t)tkn*CDIM + c) = o;
  }
}

extern "C" void kernel_launch(void* const* d_in, const int* in_sizes, int n_in,
                              void* d_out, int out_size, void* d_ws, size_t ws_size,
                              hipStream_t stream) {
  const void* x  = d_in[0];
  const void* Wr = d_in[1];
  const void* W1 = d_in[2];
  const void* b1 = d_in[3];
  const void* W2 = d_in[4];
  const void* b2 = d_in[5];

  // ws carve (all offsets multiple of 16)
  char* w = (char*)d_ws;
  int*   flagp    = (int*)w;                   // 4 B
  int*   offsets  = (int*)(w + 256);           // 9 ints
  int*   bhist    = (int*)(w + 512);           // 256 ints [512,1536)
  int*   bbase    = (int*)(w + 1536);          // 256 ints [1536,2560)
  int*   tok_e    = (int*)(w + 2560);          // 16384 ints [2560,68096)
  float* tok_w    = (float*)(w + 68096);       // [68096,133632)
  int*   tok_pos  = (int*)(w + 133632);        // [133632,199168)
  int*   pair_tok = (int*)(w + 199168);        // [199168,264704)
  u16*   b1c      = (u16*)(w + 264704);        // 49152 B [264704,313856)
  u16*   b2c      = (u16*)(w + 313856);        // 12288 B [313856,326144)
  u16*   xc       = (u16*)(w + 326144);        // 12582912 B -> 12909056
  u16*   W1t      = (u16*)(w + 12909056);      // [E][H][C] 37748736 B -> 50657792
  u16*   W2t      = W1t + (size_t)NEXP*CDIM*HDIM;      // [E][C][H] 37748736 B -> 88406528
  u16*   h        = W2t + (size_t)NEXP*CDIM*HDIM;      // [NPAIR][H] bf16 -> 189069824
  float* y        = (float*)(h + (size_t)NPAIR*HDIM);  // [NPAIR][C] fp32 -> 239401472
  size_t need = 239401472ull;
  if (ws_size < need) {
    hipMemsetAsync(d_out, 0, (size_t)out_size*2, stream);
    return;
  }

  detect_k<<<1, 256, 0, stream>>>((const u16*)x, flagp);
  // fused prep: router + W1/W2 transposes + x/b1/b2 conversions, co-scheduled in one dispatch
  mega_prep<<<MEGA_NB, 256, 0, stream>>>(x, Wr, W1, W2, b1, b2, flagp,
                                         xc, b1c, b2c, W1t, W2t, tok_e, tok_w);
  hist_k<<<HB, 256, 0, stream>>>(tok_e, bhist);
  offsets2_k<<<1, 64, 0, stream>>>(bhist, offsets, bbase, d_out, flagp);
  scatter2_k<<<HB, 256, 0, stream>>>(tok_e, bbase, pair_tok, tok_pos);
  // GEMM1: h = gelu(x_gathered @ W1[e] + b1[e])   [Me x 3072] bf16
  gemm_k<0,8><<<12288, 256, 0, stream>>>(
      xc, pair_tok, CDIM, W1t, b1c, offsets, CDIM, HDIM, h, nullptr);
  // GEMM2: y = h @ W2[e] + b2[e]                  [Me x 768] fp32
  gemm_k<1,2><<<3072, 256, 0, stream>>>(
      h, nullptr, HDIM, W2t, b2c, offsets, HDIM, CDIM, nullptr, y);
  combine_k<<<NTOK, 192, 0, stream>>>(y, tok_pos, tok_w, d_out, flagp);
}